// Round 4
// baseline (611.481 us; speedup 1.0000x reference)
//
#include <hip/hip_runtime.h>
#include <hip/hip_bf16.h>
#include <math.h>

typedef __attribute__((ext_vector_type(8))) short bf16x8;
typedef __attribute__((ext_vector_type(4))) float f32x4;

__device__ __forceinline__ float bf2f(ushort u) {
  union { unsigned u; float f; } v; v.u = ((unsigned)u) << 16; return v.f;
}
__device__ __forceinline__ ushort f2bf(float f) {
  union { float f; unsigned u; } v; v.f = f;
  unsigned r = v.u + 0x7FFFu + ((v.u >> 16) & 1u);
  return (ushort)(r >> 16);
}
#if __has_builtin(__builtin_amdgcn_exp2f)
#define EXP2F(x) __builtin_amdgcn_exp2f(x)
#else
#define EXP2F(x) exp2f(x)
#endif
__device__ __forceinline__ void gl_lds16(const ushort* g, ushort* l) {
  __builtin_amdgcn_global_load_lds(
      (const __attribute__((address_space(1))) unsigned int*)g,
      (__attribute__((address_space(3))) unsigned int*)l, 16, 0, 0);
}

// -------- workspace layout (ushort elements, after 256B header) --------
static const long XB   = 0;              // x bf16 (4096x2048); reused as attn-out
static const long WQB  = 8388608;        // wq (2048x2048)
static const long WKB  = 12582912;       // wk (512x2048)
static const long WVB  = 13631488;       // wv (512x2048)
static const long WOB  = 14680064;       // wo (2048x2048)
static const long COSB = 18874368;       // cos (2*2048*64)
static const long SINB = 19136512;       // sin
static const long QB   = 19398656;       // q (4096x2048)
static const long KB   = 27787264;       // k (4096x512)
static const long VTB  = 29884416;       // v^T (512x4096)

// ---------------- dtype detection ----------------
__global__ void detect_dtype(const ushort* __restrict__ x, int* __restrict__ flag) {
  __shared__ int cnt;
  if (threadIdx.x == 0) cnt = 0;
  __syncthreads();
  int local = 0;
  for (int j = 0; j < 32; j++) {
    ushort u = x[threadIdx.x + j * 256];
    int e = (u >> 7) & 0xFF;
    if (e >= 100 && e <= 142) local++;
  }
  atomicAdd(&cnt, local);
  __syncthreads();
  if (threadIdx.x == 0) *flag = (cnt >= 6554) ? 1 : 0;
}

// ---------------- fused cast of all 7 inputs (no-op when already bf16) --------
// segment bounds in uint4 units (16B = 8 bf16 out, 32B fp32 in)
__global__ void cast_all(const void* __restrict__ s0, const void* __restrict__ s1,
                         const void* __restrict__ s2, const void* __restrict__ s3,
                         const void* __restrict__ s4, const void* __restrict__ s5,
                         const void* __restrict__ s6,
                         ushort* __restrict__ d0, ushort* __restrict__ d1,
                         ushort* __restrict__ d2, ushort* __restrict__ d3,
                         ushort* __restrict__ d4, ushort* __restrict__ d5,
                         ushort* __restrict__ d6, const int* __restrict__ flag) {
  if (*flag) return;
  const long N = 2424832;
  for (long i = (long)blockIdx.x * blockDim.x + threadIdx.x; i < N;
       i += (long)gridDim.x * blockDim.x) {
    const float4* s; ushort* d; long off;
    if      (i < 1048576) { s = (const float4*)s0; d = d0; off = i; }
    else if (i < 1572864) { s = (const float4*)s1; d = d1; off = i - 1048576; }
    else if (i < 1703936) { s = (const float4*)s2; d = d2; off = i - 1572864; }
    else if (i < 1835008) { s = (const float4*)s3; d = d3; off = i - 1703936; }
    else if (i < 2359296) { s = (const float4*)s4; d = d4; off = i - 1835008; }
    else if (i < 2392064) { s = (const float4*)s5; d = d5; off = i - 2359296; }
    else                  { s = (const float4*)s6; d = d6; off = i - 2392064; }
    float4 a = s[2 * off], b = s[2 * off + 1];
    uint4 o;
    o.x = (unsigned)f2bf(a.x) | ((unsigned)f2bf(a.y) << 16);
    o.y = (unsigned)f2bf(a.z) | ((unsigned)f2bf(a.w) << 16);
    o.z = (unsigned)f2bf(b.x) | ((unsigned)f2bf(b.y) << 16);
    o.w = (unsigned)f2bf(b.z) | ((unsigned)f2bf(b.w) << 16);
    ((uint4*)d)[off] = o;
  }
}

// ---------------- bf16 GEMM body: C tile = A[M,K] * W[N,K]^T ----------------
__device__ __forceinline__ void gemm_body(
    const ushort* __restrict__ A, const ushort* __restrict__ W, void* __restrict__ C,
    int N, int K, int bm, int bn, bool ofp32, ushort* As, ushort* Ws) {
  const int tid = threadIdx.x;
  const int wave = tid >> 6, lane = tid & 63;
  const int quad = lane >> 4, l15 = lane & 15;
  const int wm = (wave >> 1) * 64, wn = (wave & 1) * 64;
  const int srow = tid >> 2, sk = (tid & 3) * 8;
  const ushort* Ap = A + (size_t)(bm + srow) * K + sk;
  const ushort* Wp = W + (size_t)(bn + srow) * K + sk;
  ushort* AsW = As + wave * 512;
  ushort* WsW = Ws + wave * 512;
  f32x4 acc[4][4] = {};
  for (int k0 = 0; k0 < K; k0 += 32) {
    __syncthreads();
    gl_lds16(Ap + k0, AsW);
    gl_lds16(Ap + (size_t)64 * K + k0, AsW + 2048);
    gl_lds16(Wp + k0, WsW);
    gl_lds16(Wp + (size_t)64 * K + k0, WsW + 2048);
    __syncthreads();
    bf16x8 af[4], wf[4];
#pragma unroll
    for (int t = 0; t < 4; t++)
      af[t] = *(const bf16x8*)&As[(wm + t * 16 + l15) * 32 + quad * 8];
#pragma unroll
    for (int t = 0; t < 4; t++)
      wf[t] = *(const bf16x8*)&Ws[(wn + t * 16 + l15) * 32 + quad * 8];
#pragma unroll
    for (int mt = 0; mt < 4; mt++)
#pragma unroll
      for (int nt = 0; nt < 4; nt++)
        acc[mt][nt] = __builtin_amdgcn_mfma_f32_16x16x32_bf16(af[mt], wf[nt], acc[mt][nt], 0, 0, 0);
  }
  if (!ofp32) {
    ushort* Cb = (ushort*)C;
#pragma unroll
    for (int mt = 0; mt < 4; mt++)
#pragma unroll
      for (int nt = 0; nt < 4; nt++)
#pragma unroll
        for (int r = 0; r < 4; r++) {
          int row = bm + wm + mt * 16 + quad * 4 + r;
          int col = bn + wn + nt * 16 + l15;
          Cb[(size_t)row * N + col] = f2bf(acc[mt][nt][r]);
        }
  } else {
    float* Cf = (float*)C;
#pragma unroll
    for (int mt = 0; mt < 4; mt++)
#pragma unroll
      for (int nt = 0; nt < 4; nt++)
#pragma unroll
        for (int r = 0; r < 4; r++) {
          int row = bm + wm + mt * 16 + quad * 4 + r;
          int col = bn + wn + nt * 16 + l15;
          Cf[(size_t)row * N + col] = acc[mt][nt][r];
        }
  }
}

// fused Q/K/V^T projection: 1D grid 768. [0,512) Q; [512,640) K; [640,768) V^T.
__global__ __launch_bounds__(256) void gemm_qkv(
    const ushort* __restrict__ xws, const ushort* __restrict__ xorig,
    const ushort* __restrict__ wqws, const ushort* __restrict__ wqorig,
    const ushort* __restrict__ wkws, const ushort* __restrict__ wkorig,
    const ushort* __restrict__ wvws, const ushort* __restrict__ wvorig,
    ushort* __restrict__ qout, ushort* __restrict__ kout, ushort* __restrict__ vtout,
    const int* __restrict__ flag) {
  __shared__ __align__(16) ushort As[128 * 32];
  __shared__ __align__(16) ushort Ws[128 * 32];
  const bool bf = (*flag != 0);
  const ushort* x = bf ? xorig : xws;
  const int id = blockIdx.x;
  if (id < 512) {
    gemm_body(x, bf ? wqorig : wqws, qout, 2048, 2048, (id >> 4) * 128, (id & 15) * 128, false, As, Ws);
  } else if (id < 640) {
    int t = id - 512;
    gemm_body(x, bf ? wkorig : wkws, kout, 512, 2048, (t >> 2) * 128, (t & 3) * 128, false, As, Ws);
  } else {
    int t = id - 640;
    gemm_body(bf ? wvorig : wvws, x, vtout, 4096, 2048, (t & 3) * 128, (t >> 2) * 128, false, As, Ws);
  }
}

__global__ __launch_bounds__(256) void gemm_bt(
    const ushort* __restrict__ Aws, const ushort* __restrict__ Aorig,
    const ushort* __restrict__ Wws, const ushort* __restrict__ Worig,
    void* __restrict__ C, int N, int K, const int* __restrict__ flag, int outMode) {
  __shared__ __align__(16) ushort As[128 * 32];
  __shared__ __align__(16) ushort Ws[128 * 32];
  const bool bf = (*flag != 0);
  const ushort* A = (bf && Aorig) ? Aorig : Aws;
  const ushort* W = (bf && Worig) ? Worig : Wws;
  bool ofp32 = (outMode == 1) && !bf;
  gemm_body(A, W, C, N, K, blockIdx.y * 128, blockIdx.x * 128, ofp32, As, Ws);
}

// ---------------- RoPE, vectorized: 16 elems/thread ----------------
// Q gets 0.125*log2(e) folded in (exp2 softmax path).
__global__ void rope_kernel(ushort* __restrict__ Qb, ushort* __restrict__ Kb,
                            const ushort* __restrict__ cws, const ushort* __restrict__ corig,
                            const ushort* __restrict__ sws, const ushort* __restrict__ sorig,
                            const int* __restrict__ flag) {
  const ushort* cb = (*flag) ? corig : cws;
  const ushort* sb = (*flag) ? sorig : sws;
  int i = blockIdx.x * 256 + threadIdx.x;   // 0..655359
  ushort* base; long row; int c8; float scl;
  if (i < 524288) {
    row = i >> 7; int rest = i & 127; c8 = (rest & 3) * 8;
    base = Qb + row * 2048 + (rest >> 2) * 64 + c8;
    scl = 0.18033688011112f;   // 0.125 * log2(e)
  } else {
    int j = i - 524288;
    row = j >> 5; int rest = j & 31; c8 = (rest & 3) * 8;
    base = Kb + row * 512 + (rest >> 2) * 64 + c8;
    scl = 1.0f;
  }
  uint4 lo4 = *(const uint4*)base;
  uint4 hi4 = *(const uint4*)(base + 32);
  uint4 cl4 = *(const uint4*)(cb + row * 64 + c8);
  uint4 ch4 = *(const uint4*)(cb + row * 64 + c8 + 32);
  uint4 sl4 = *(const uint4*)(sb + row * 64 + c8);
  uint4 sh4 = *(const uint4*)(sb + row * 64 + c8 + 32);
  const ushort* lo = (const ushort*)&lo4; const ushort* hi = (const ushort*)&hi4;
  const ushort* cl = (const ushort*)&cl4; const ushort* ch = (const ushort*)&ch4;
  const ushort* sl = (const ushort*)&sl4; const ushort* sh = (const ushort*)&sh4;
  uint4 olo, ohi;
  ushort* po = (ushort*)&olo; ushort* ph = (ushort*)&ohi;
#pragma unroll
  for (int k = 0; k < 8; k++) {
    float l = bf2f(lo[k]), h = bf2f(hi[k]);
    po[k] = f2bf((l * bf2f(cl[k]) - h * bf2f(sl[k])) * scl);
    ph[k] = f2bf((h * bf2f(ch[k]) + l * bf2f(sh[k])) * scl);
  }
  *(uint4*)base = olo;
  *(uint4*)(base + 32) = ohi;
}

// ---------------- causal GQA flash attention, K/V from L2 ----------------
// 2-wave blocks, 32 Q rows/wave. Block pr processes 64-row Q-blocks pr AND
// 31-pr: every wave = exactly 33 KV-tile iterations -> perfect static balance,
// grid 2048 = 8 blocks/CU = 16 waves/CU resident. No barriers anywhere.
__global__ __launch_bounds__(128, 5) void attn_kernel(
    const ushort* __restrict__ Qb, const ushort* __restrict__ Kb,
    const ushort* __restrict__ Vt, ushort* __restrict__ Ob) {
  constexpr int LDT = 72;
  __shared__ __align__(16) ushort Ps[64 * LDT];
  const int tid = threadIdx.x;
  const int wave = tid >> 6, lane = tid & 63;
  const int quad = lane >> 4, l15 = lane & 15;
  const int id = blockIdx.x;
  const int kvh = id & 7;
  const int b = (id >> 3) & 1;
  const int hsub = (id >> 4) & 3;
  const int h = kvh * 4 + hsub;
  const int pr = id >> 6;                  // 0..31
  const size_t brow = (size_t)b * 2048;
  const ushort* Kg = Kb + brow * 512 + (size_t)kvh * 64;
  const ushort* Vg = Vt + (size_t)(kvh * 64) * 4096 + brow;
  ushort* PsW = Ps + (wave * 32) * LDT;

  for (int ph = 0; ph < 2; ph++) {
    const int P = ph ? (31 - pr) : pr;     // 64-row Q-block index
    const int wrow0 = P * 64 + wave * 32;
    const int ntEnd = P + 1;

    bf16x8 qf[2][2];
#pragma unroll
    for (int mt = 0; mt < 2; mt++)
#pragma unroll
      for (int kc = 0; kc < 2; kc++)
        qf[mt][kc] = *(const bf16x8*)&Qb[(brow + wrow0 + mt * 16 + l15) * 2048 + h * 64 + kc * 32 + quad * 8];

    float l_s[2][4] = {};
    f32x4 oacc[2][4] = {};

    for (int nt = 0; nt < ntEnd; nt++) {
      const int n0 = nt * 64;
      bf16x8 kf[4][2];
#pragma unroll
      for (int ct = 0; ct < 4; ct++)
#pragma unroll
        for (int kc = 0; kc < 2; kc++)
          kf[ct][kc] = *(const bf16x8*)&Kg[(size_t)(n0 + ct * 16 + l15) * 512 + kc * 32 + quad * 8];
      const bool diag = (nt == ntEnd - 1);
#pragma unroll
      for (int mt = 0; mt < 2; mt++) {
        f32x4 sc[4];
#pragma unroll
        for (int ct = 0; ct < 4; ct++) {
          f32x4 z = {0.f, 0.f, 0.f, 0.f};
          z = __builtin_amdgcn_mfma_f32_16x16x32_bf16(qf[mt][0], kf[ct][0], z, 0, 0, 0);
          z = __builtin_amdgcn_mfma_f32_16x16x32_bf16(qf[mt][1], kf[ct][1], z, 0, 0, 0);
          sc[ct] = z;
        }
        const int rowb = wrow0 + mt * 16 + quad * 4;
        if (diag) {
#pragma unroll
          for (int ct = 0; ct < 4; ct++)
#pragma unroll
            for (int r = 0; r < 4; r++)
              if (n0 + ct * 16 + l15 > rowb + r) sc[ct][r] = -INFINITY;
        }
#pragma unroll
        for (int ct = 0; ct < 4; ct++)
#pragma unroll
          for (int r = 0; r < 4; r++) {
            float pv = EXP2F(sc[ct][r] - 23.083120654223f);
            l_s[mt][r] += pv;
            PsW[(mt * 16 + quad * 4 + r) * LDT + ct * 16 + l15] =
                (ushort)((__float_as_uint(pv) + 0x8000u) >> 16);
          }
      }
      bf16x8 vf[4][2];
#pragma unroll
      for (int dt = 0; dt < 4; dt++)
#pragma unroll
        for (int kc = 0; kc < 2; kc++)
          vf[dt][kc] = *(const bf16x8*)&Vg[(size_t)(dt * 16 + l15) * 4096 + n0 + kc * 32 + quad * 8];
      bf16x8 pf[2][2];
#pragma unroll
      for (int mt = 0; mt < 2; mt++)
#pragma unroll
        for (int kc = 0; kc < 2; kc++)
          pf[mt][kc] = *(const bf16x8*)&PsW[(mt * 16 + l15) * LDT + kc * 32 + quad * 8];
#pragma unroll
      for (int dt = 0; dt < 4; dt++)
#pragma unroll
        for (int mt = 0; mt < 2; mt++) {
          oacc[mt][dt] = __builtin_amdgcn_mfma_f32_16x16x32_bf16(pf[mt][0], vf[dt][0], oacc[mt][dt], 0, 0, 0);
          oacc[mt][dt] = __builtin_amdgcn_mfma_f32_16x16x32_bf16(pf[mt][1], vf[dt][1], oacc[mt][dt], 0, 0, 0);
        }
    }
#pragma unroll
    for (int mt = 0; mt < 2; mt++)
#pragma unroll
      for (int r = 0; r < 4; r++) {
        float l = l_s[mt][r];
#pragma unroll
        for (int off = 1; off < 16; off <<= 1) l += __shfl_xor(l, off, 64);
        l_s[mt][r] = 1.f / l;
      }
#pragma unroll
    for (int mt = 0; mt < 2; mt++)
#pragma unroll
      for (int dt = 0; dt < 4; dt++)
#pragma unroll
        for (int r = 0; r < 4; r++) {
          int s = wrow0 + mt * 16 + quad * 4 + r;
          Ob[(brow + s) * 2048 + h * 64 + dt * 16 + l15] = f2bf(oacc[mt][dt][r] * l_s[mt][r]);
        }
  }
}

extern "C" void kernel_launch(void* const* d_in, const int* in_sizes, int n_in,
                              void* d_out, int out_size, void* d_ws, size_t ws_size,
                              hipStream_t stream) {
  char* wsb = (char*)d_ws;
  int* flag = (int*)wsb;
  ushort* base = (ushort*)(wsb + 256);
  ushort* xb   = base + XB;
  ushort* wqb  = base + WQB;
  ushort* wkb  = base + WKB;
  ushort* wvb  = base + WVB;
  ushort* wob  = base + WOB;
  ushort* cosb = base + COSB;
  ushort* sinb = base + SINB;
  ushort* qb   = base + QB;
  ushort* kb   = base + KB;
  ushort* vtb  = base + VTB;
  ushort* abuf = xb;   // attn output reuses x region

  const ushort* xo  = (const ushort*)d_in[0];
  const ushort* co  = (const ushort*)d_in[1];
  const ushort* so  = (const ushort*)d_in[2];
  const ushort* wqo = (const ushort*)d_in[4];
  const ushort* wko = (const ushort*)d_in[5];
  const ushort* wvo = (const ushort*)d_in[6];
  const ushort* woo = (const ushort*)d_in[7];

  detect_dtype<<<1, 256, 0, stream>>>(xo, flag);

  cast_all<<<4096, 256, 0, stream>>>(d_in[0], d_in[4], d_in[5], d_in[6], d_in[7],
                                     d_in[1], d_in[2],
                                     xb, wqb, wkb, wvb, wob, cosb, sinb, flag);

  gemm_qkv<<<768, 256, 0, stream>>>(xb, xo, wqb, wqo, wkb, wko, wvb, wvo,
                                    qb, kb, vtb, flag);

  rope_kernel<<<2560, 256, 0, stream>>>(qb, kb, cosb, co, sinb, so, flag);

  attn_kernel<<<2048, 128, 0, stream>>>(qb, kb, vtb, abuf);

  gemm_bt<<<dim3(16, 32), 256, 0, stream>>>(abuf, nullptr, wob, woo, d_out, 2048, 2048, flag, 1);
}

// Round 5
// 500.498 us; speedup vs baseline: 1.2217x; 1.2217x over previous
//
#include <hip/hip_runtime.h>
#include <hip/hip_bf16.h>
#include <math.h>

typedef __attribute__((ext_vector_type(8))) short bf16x8;
typedef __attribute__((ext_vector_type(4))) float f32x4;

__device__ __forceinline__ float bf2f(ushort u) {
  union { unsigned u; float f; } v; v.u = ((unsigned)u) << 16; return v.f;
}
__device__ __forceinline__ ushort f2bf(float f) {
  union { float f; unsigned u; } v; v.f = f;
  unsigned r = v.u + 0x7FFFu + ((v.u >> 16) & 1u);
  return (ushort)(r >> 16);
}
#if __has_builtin(__builtin_amdgcn_exp2f)
#define EXP2F(x) __builtin_amdgcn_exp2f(x)
#else
#define EXP2F(x) exp2f(x)
#endif
__device__ __forceinline__ void gl_lds16(const ushort* g, ushort* l) {
  __builtin_amdgcn_global_load_lds(
      (const __attribute__((address_space(1))) unsigned int*)g,
      (__attribute__((address_space(3))) unsigned int*)l, 16, 0, 0);
}

// -------- workspace layout (ushort elements, after 256B header) --------
static const long XB   = 0;              // x bf16 (4096x2048); reused as attn-out
static const long WQB  = 8388608;        // wq (2048x2048)
static const long WKB  = 12582912;       // wk (512x2048)
static const long WVB  = 13631488;       // wv (512x2048)
static const long WOB  = 14680064;       // wo (2048x2048)
static const long COSB = 18874368;       // cos (2*2048*64)
static const long SINB = 19136512;       // sin
static const long QB   = 19398656;       // q (4096x2048)
static const long KB   = 27787264;       // k (4096x512)
static const long VTB  = 29884416;       // v^T (512x4096)

// ---------------- dtype detection ----------------
__global__ void detect_dtype(const ushort* __restrict__ x, int* __restrict__ flag) {
  __shared__ int cnt;
  if (threadIdx.x == 0) cnt = 0;
  __syncthreads();
  int local = 0;
  for (int j = 0; j < 32; j++) {
    ushort u = x[threadIdx.x + j * 256];
    int e = (u >> 7) & 0xFF;
    if (e >= 100 && e <= 142) local++;
  }
  atomicAdd(&cnt, local);
  __syncthreads();
  if (threadIdx.x == 0) *flag = (cnt >= 6554) ? 1 : 0;
}

// ---------------- fused cast of all 7 inputs (no-op when already bf16) --------
__global__ void cast_all(const void* __restrict__ s0, const void* __restrict__ s1,
                         const void* __restrict__ s2, const void* __restrict__ s3,
                         const void* __restrict__ s4, const void* __restrict__ s5,
                         const void* __restrict__ s6,
                         ushort* __restrict__ d0, ushort* __restrict__ d1,
                         ushort* __restrict__ d2, ushort* __restrict__ d3,
                         ushort* __restrict__ d4, ushort* __restrict__ d5,
                         ushort* __restrict__ d6, const int* __restrict__ flag) {
  if (*flag) return;
  const long N = 2424832;
  for (long i = (long)blockIdx.x * blockDim.x + threadIdx.x; i < N;
       i += (long)gridDim.x * blockDim.x) {
    const float4* s; ushort* d; long off;
    if      (i < 1048576) { s = (const float4*)s0; d = d0; off = i; }
    else if (i < 1572864) { s = (const float4*)s1; d = d1; off = i - 1048576; }
    else if (i < 1703936) { s = (const float4*)s2; d = d2; off = i - 1572864; }
    else if (i < 1835008) { s = (const float4*)s3; d = d3; off = i - 1703936; }
    else if (i < 2359296) { s = (const float4*)s4; d = d4; off = i - 1835008; }
    else if (i < 2392064) { s = (const float4*)s5; d = d5; off = i - 2359296; }
    else                  { s = (const float4*)s6; d = d6; off = i - 2392064; }
    float4 a = s[2 * off], b = s[2 * off + 1];
    uint4 o;
    o.x = (unsigned)f2bf(a.x) | ((unsigned)f2bf(a.y) << 16);
    o.y = (unsigned)f2bf(a.z) | ((unsigned)f2bf(a.w) << 16);
    o.z = (unsigned)f2bf(b.x) | ((unsigned)f2bf(b.y) << 16);
    o.w = (unsigned)f2bf(b.z) | ((unsigned)f2bf(b.w) << 16);
    ((uint4*)d)[off] = o;
  }
}

// ---------------- bf16 GEMM body: C tile = A[M,K] * W[N,K]^T ----------------
__device__ __forceinline__ void gemm_body(
    const ushort* __restrict__ A, const ushort* __restrict__ W, void* __restrict__ C,
    int N, int K, int bm, int bn, bool ofp32, ushort* As, ushort* Ws) {
  const int tid = threadIdx.x;
  const int wave = tid >> 6, lane = tid & 63;
  const int quad = lane >> 4, l15 = lane & 15;
  const int wm = (wave >> 1) * 64, wn = (wave & 1) * 64;
  const int srow = tid >> 2, sk = (tid & 3) * 8;
  const ushort* Ap = A + (size_t)(bm + srow) * K + sk;
  const ushort* Wp = W + (size_t)(bn + srow) * K + sk;
  ushort* AsW = As + wave * 512;
  ushort* WsW = Ws + wave * 512;
  f32x4 acc[4][4] = {};
  for (int k0 = 0; k0 < K; k0 += 32) {
    __syncthreads();
    gl_lds16(Ap + k0, AsW);
    gl_lds16(Ap + (size_t)64 * K + k0, AsW + 2048);
    gl_lds16(Wp + k0, WsW);
    gl_lds16(Wp + (size_t)64 * K + k0, WsW + 2048);
    __syncthreads();
    bf16x8 af[4], wf[4];
#pragma unroll
    for (int t = 0; t < 4; t++)
      af[t] = *(const bf16x8*)&As[(wm + t * 16 + l15) * 32 + quad * 8];
#pragma unroll
    for (int t = 0; t < 4; t++)
      wf[t] = *(const bf16x8*)&Ws[(wn + t * 16 + l15) * 32 + quad * 8];
#pragma unroll
    for (int mt = 0; mt < 4; mt++)
#pragma unroll
      for (int nt = 0; nt < 4; nt++)
        acc[mt][nt] = __builtin_amdgcn_mfma_f32_16x16x32_bf16(af[mt], wf[nt], acc[mt][nt], 0, 0, 0);
  }
  if (!ofp32) {
    ushort* Cb = (ushort*)C;
#pragma unroll
    for (int mt = 0; mt < 4; mt++)
#pragma unroll
      for (int nt = 0; nt < 4; nt++)
#pragma unroll
        for (int r = 0; r < 4; r++) {
          int row = bm + wm + mt * 16 + quad * 4 + r;
          int col = bn + wn + nt * 16 + l15;
          Cb[(size_t)row * N + col] = f2bf(acc[mt][nt][r]);
        }
  } else {
    float* Cf = (float*)C;
#pragma unroll
    for (int mt = 0; mt < 4; mt++)
#pragma unroll
      for (int nt = 0; nt < 4; nt++)
#pragma unroll
        for (int r = 0; r < 4; r++) {
          int row = bm + wm + mt * 16 + quad * 4 + r;
          int col = bn + wn + nt * 16 + l15;
          Cf[(size_t)row * N + col] = acc[mt][nt][r];
        }
  }
}

// fused Q/K/V^T projection: 1D grid 768. [0,512) Q; [512,640) K; [640,768) V^T.
__global__ __launch_bounds__(256) void gemm_qkv(
    const ushort* __restrict__ xws, const ushort* __restrict__ xorig,
    const ushort* __restrict__ wqws, const ushort* __restrict__ wqorig,
    const ushort* __restrict__ wkws, const ushort* __restrict__ wkorig,
    const ushort* __restrict__ wvws, const ushort* __restrict__ wvorig,
    ushort* __restrict__ qout, ushort* __restrict__ kout, ushort* __restrict__ vtout,
    const int* __restrict__ flag) {
  __shared__ __align__(16) ushort As[128 * 32];
  __shared__ __align__(16) ushort Ws[128 * 32];
  const bool bf = (*flag != 0);
  const ushort* x = bf ? xorig : xws;
  const int id = blockIdx.x;
  if (id < 512) {
    gemm_body(x, bf ? wqorig : wqws, qout, 2048, 2048, (id >> 4) * 128, (id & 15) * 128, false, As, Ws);
  } else if (id < 640) {
    int t = id - 512;
    gemm_body(x, bf ? wkorig : wkws, kout, 512, 2048, (t >> 2) * 128, (t & 3) * 128, false, As, Ws);
  } else {
    int t = id - 640;
    gemm_body(bf ? wvorig : wvws, x, vtout, 4096, 2048, (t & 3) * 128, (t >> 2) * 128, false, As, Ws);
  }
}

__global__ __launch_bounds__(256) void gemm_bt(
    const ushort* __restrict__ Aws, const ushort* __restrict__ Aorig,
    const ushort* __restrict__ Wws, const ushort* __restrict__ Worig,
    void* __restrict__ C, int N, int K, const int* __restrict__ flag, int outMode) {
  __shared__ __align__(16) ushort As[128 * 32];
  __shared__ __align__(16) ushort Ws[128 * 32];
  const bool bf = (*flag != 0);
  const ushort* A = (bf && Aorig) ? Aorig : Aws;
  const ushort* W = (bf && Worig) ? Worig : Wws;
  bool ofp32 = (outMode == 1) && !bf;
  gemm_body(A, W, C, N, K, blockIdx.y * 128, blockIdx.x * 128, ofp32, As, Ws);
}

// ---------------- RoPE, vectorized: 16 elems/thread ----------------
__global__ void rope_kernel(ushort* __restrict__ Qb, ushort* __restrict__ Kb,
                            const ushort* __restrict__ cws, const ushort* __restrict__ corig,
                            const ushort* __restrict__ sws, const ushort* __restrict__ sorig,
                            const int* __restrict__ flag) {
  const ushort* cb = (*flag) ? corig : cws;
  const ushort* sb = (*flag) ? sorig : sws;
  int i = blockIdx.x * 256 + threadIdx.x;   // 0..655359
  ushort* base; long row; int c8; float scl;
  if (i < 524288) {
    row = i >> 7; int rest = i & 127; c8 = (rest & 3) * 8;
    base = Qb + row * 2048 + (rest >> 2) * 64 + c8;
    scl = 0.18033688011112f;   // 0.125 * log2(e)
  } else {
    int j = i - 524288;
    row = j >> 5; int rest = j & 31; c8 = (rest & 3) * 8;
    base = Kb + row * 512 + (rest >> 2) * 64 + c8;
    scl = 1.0f;
  }
  uint4 lo4 = *(const uint4*)base;
  uint4 hi4 = *(const uint4*)(base + 32);
  uint4 cl4 = *(const uint4*)(cb + row * 64 + c8);
  uint4 ch4 = *(const uint4*)(cb + row * 64 + c8 + 32);
  uint4 sl4 = *(const uint4*)(sb + row * 64 + c8);
  uint4 sh4 = *(const uint4*)(sb + row * 64 + c8 + 32);
  const ushort* lo = (const ushort*)&lo4; const ushort* hi = (const ushort*)&hi4;
  const ushort* cl = (const ushort*)&cl4; const ushort* ch = (const ushort*)&ch4;
  const ushort* sl = (const ushort*)&sl4; const ushort* sh = (const ushort*)&sh4;
  uint4 olo, ohi;
  ushort* po = (ushort*)&olo; ushort* ph = (ushort*)&ohi;
#pragma unroll
  for (int k = 0; k < 8; k++) {
    float l = bf2f(lo[k]), h = bf2f(hi[k]);
    po[k] = f2bf((l * bf2f(cl[k]) - h * bf2f(sl[k])) * scl);
    ph[k] = f2bf((h * bf2f(ch[k]) + l * bf2f(sh[k])) * scl);
  }
  *(uint4*)base = olo;
  *(uint4*)(base + 32) = ohi;
}

// ---------------- causal GQA flash attention, K/V from L2 ----------------
// 2-wave blocks, 32 Q rows/wave. Block pr processes 64-row Q-blocks pr AND
// 31-pr: every wave = exactly 33 KV-tile iterations. Grid 2048 = 8 blocks/CU.
// __launch_bounds__(128,4): VGPR budget 128 — R4's (128,5) capped at ~102 and
// SPILLED (WRITE_SIZE 416MB of scratch). Body needs ~84-100 VGPRs.
__global__ __launch_bounds__(128, 4) void attn_kernel(
    const ushort* __restrict__ Qb, const ushort* __restrict__ Kb,
    const ushort* __restrict__ Vt, ushort* __restrict__ Ob) {
  constexpr int LDT = 72;
  __shared__ __align__(16) ushort Ps[64 * LDT];
  const int tid = threadIdx.x;
  const int wave = tid >> 6, lane = tid & 63;
  const int quad = lane >> 4, l15 = lane & 15;
  const int id = blockIdx.x;
  const int kvh = id & 7;
  const int b = (id >> 3) & 1;
  const int hsub = (id >> 4) & 3;
  const int h = kvh * 4 + hsub;
  const int pr = id >> 6;                  // 0..31
  const size_t brow = (size_t)b * 2048;
  const ushort* Kg = Kb + brow * 512 + (size_t)kvh * 64;
  const ushort* Vg = Vt + (size_t)(kvh * 64) * 4096 + brow;
  ushort* PsW = Ps + (wave * 32) * LDT;

  for (int ph = 0; ph < 2; ph++) {
    const int P = ph ? (31 - pr) : pr;     // 64-row Q-block index
    const int wrow0 = P * 64 + wave * 32;
    const int ntEnd = P + 1;

    bf16x8 qf[2][2];
#pragma unroll
    for (int mt = 0; mt < 2; mt++)
#pragma unroll
      for (int kc = 0; kc < 2; kc++)
        qf[mt][kc] = *(const bf16x8*)&Qb[(brow + wrow0 + mt * 16 + l15) * 2048 + h * 64 + kc * 32 + quad * 8];

    float l_s[2][4] = {};
    f32x4 oacc[2][4] = {};

    for (int nt = 0; nt < ntEnd; nt++) {
      const int n0 = nt * 64;
      bf16x8 kf[4][2];
#pragma unroll
      for (int ct = 0; ct < 4; ct++)
#pragma unroll
        for (int kc = 0; kc < 2; kc++)
          kf[ct][kc] = *(const bf16x8*)&Kg[(size_t)(n0 + ct * 16 + l15) * 512 + kc * 32 + quad * 8];
      const bool diag = (nt == ntEnd - 1);
#pragma unroll
      for (int mt = 0; mt < 2; mt++) {
        f32x4 sc[4];
#pragma unroll
        for (int ct = 0; ct < 4; ct++) {
          f32x4 z = {0.f, 0.f, 0.f, 0.f};
          z = __builtin_amdgcn_mfma_f32_16x16x32_bf16(qf[mt][0], kf[ct][0], z, 0, 0, 0);
          z = __builtin_amdgcn_mfma_f32_16x16x32_bf16(qf[mt][1], kf[ct][1], z, 0, 0, 0);
          sc[ct] = z;
        }
        const int rowb = wrow0 + mt * 16 + quad * 4;
        if (diag) {
#pragma unroll
          for (int ct = 0; ct < 4; ct++)
#pragma unroll
            for (int r = 0; r < 4; r++)
              if (n0 + ct * 16 + l15 > rowb + r) sc[ct][r] = -INFINITY;
        }
#pragma unroll
        for (int ct = 0; ct < 4; ct++)
#pragma unroll
          for (int r = 0; r < 4; r++) {
            float pv = EXP2F(sc[ct][r] - 23.083120654223f);
            l_s[mt][r] += pv;
            PsW[(mt * 16 + quad * 4 + r) * LDT + ct * 16 + l15] =
                (ushort)((__float_as_uint(pv) + 0x8000u) >> 16);
          }
      }
      bf16x8 vf[4][2];
#pragma unroll
      for (int dt = 0; dt < 4; dt++)
#pragma unroll
        for (int kc = 0; kc < 2; kc++)
          vf[dt][kc] = *(const bf16x8*)&Vg[(size_t)(dt * 16 + l15) * 4096 + n0 + kc * 32 + quad * 8];
      bf16x8 pf[2][2];
#pragma unroll
      for (int mt = 0; mt < 2; mt++)
#pragma unroll
        for (int kc = 0; kc < 2; kc++)
          pf[mt][kc] = *(const bf16x8*)&PsW[(mt * 16 + l15) * LDT + kc * 32 + quad * 8];
#pragma unroll
      for (int dt = 0; dt < 4; dt++)
#pragma unroll
        for (int mt = 0; mt < 2; mt++) {
          oacc[mt][dt] = __builtin_amdgcn_mfma_f32_16x16x32_bf16(pf[mt][0], vf[dt][0], oacc[mt][dt], 0, 0, 0);
          oacc[mt][dt] = __builtin_amdgcn_mfma_f32_16x16x32_bf16(pf[mt][1], vf[dt][1], oacc[mt][dt], 0, 0, 0);
        }
    }
#pragma unroll
    for (int mt = 0; mt < 2; mt++)
#pragma unroll
      for (int r = 0; r < 4; r++) {
        float l = l_s[mt][r];
#pragma unroll
        for (int off = 1; off < 16; off <<= 1) l += __shfl_xor(l, off, 64);
        l_s[mt][r] = 1.f / l;
      }
#pragma unroll
    for (int mt = 0; mt < 2; mt++)
#pragma unroll
      for (int dt = 0; dt < 4; dt++)
#pragma unroll
        for (int r = 0; r < 4; r++) {
          int s = wrow0 + mt * 16 + quad * 4 + r;
          Ob[(brow + s) * 2048 + h * 64 + dt * 16 + l15] = f2bf(oacc[mt][dt][r] * l_s[mt][r]);
        }
  }
}

extern "C" void kernel_launch(void* const* d_in, const int* in_sizes, int n_in,
                              void* d_out, int out_size, void* d_ws, size_t ws_size,
                              hipStream_t stream) {
  char* wsb = (char*)d_ws;
  int* flag = (int*)wsb;
  ushort* base = (ushort*)(wsb + 256);
  ushort* xb   = base + XB;
  ushort* wqb  = base + WQB;
  ushort* wkb  = base + WKB;
  ushort* wvb  = base + WVB;
  ushort* wob  = base + WOB;
  ushort* cosb = base + COSB;
  ushort* sinb = base + SINB;
  ushort* qb   = base + QB;
  ushort* kb   = base + KB;
  ushort* vtb  = base + VTB;
  ushort* abuf = xb;   // attn output reuses x region

  const ushort* xo  = (const ushort*)d_in[0];
  const ushort* co  = (const ushort*)d_in[1];
  const ushort* so  = (const ushort*)d_in[2];
  const ushort* wqo = (const ushort*)d_in[4];
  const ushort* wko = (const ushort*)d_in[5];
  const ushort* wvo = (const ushort*)d_in[6];
  const ushort* woo = (const ushort*)d_in[7];

  detect_dtype<<<1, 256, 0, stream>>>(xo, flag);

  cast_all<<<4096, 256, 0, stream>>>(d_in[0], d_in[4], d_in[5], d_in[6], d_in[7],
                                     d_in[1], d_in[2],
                                     xb, wqb, wkb, wvb, wob, cosb, sinb, flag);

  gemm_qkv<<<768, 256, 0, stream>>>(xb, xo, wqb, wqo, wkb, wko, wvb, wvo,
                                    qb, kb, vtb, flag);

  rope_kernel<<<2560, 256, 0, stream>>>(qb, kb, cosb, co, sinb, so, flag);

  attn_kernel<<<2048, 128, 0, stream>>>(qb, kb, vtb, abuf);

  gemm_bt<<<dim3(16, 32), 256, 0, stream>>>(abuf, nullptr, wob, woo, d_out, 2048, 2048, flag, 1);
}

// Round 6
// 327.728 us; speedup vs baseline: 1.8658x; 1.5272x over previous
//
#include <hip/hip_runtime.h>
#include <hip/hip_bf16.h>
#include <math.h>

typedef __attribute__((ext_vector_type(8))) short bf16x8;
typedef __attribute__((ext_vector_type(4))) float f32x4;

__device__ __forceinline__ float bf2f(ushort u) {
  union { unsigned u; float f; } v; v.u = ((unsigned)u) << 16; return v.f;
}
__device__ __forceinline__ ushort f2bf(float f) {
  union { float f; unsigned u; } v; v.f = f;
  unsigned r = v.u + 0x7FFFu + ((v.u >> 16) & 1u);
  return (ushort)(r >> 16);
}
#if __has_builtin(__builtin_amdgcn_exp2f)
#define EXP2F(x) __builtin_amdgcn_exp2f(x)
#else
#define EXP2F(x) exp2f(x)
#endif
__device__ __forceinline__ void gl_lds16(const ushort* g, ushort* l) {
  __builtin_amdgcn_global_load_lds(
      (const __attribute__((address_space(1))) unsigned int*)g,
      (__attribute__((address_space(3))) unsigned int*)l, 16, 0, 0);
}

// -------- workspace layout (ushort elements, after 256B header) --------
static const long XB   = 0;              // x bf16 (4096x2048); reused as attn-out
static const long WQB  = 8388608;        // wq (2048x2048)
static const long WKB  = 12582912;       // wk (512x2048)
static const long WVB  = 13631488;       // wv (512x2048)
static const long WOB  = 14680064;       // wo (2048x2048)
static const long COSB = 18874368;       // cos (2*2048*64)
static const long SINB = 19136512;       // sin
static const long QB   = 19398656;       // q (4096x2048)
static const long KB   = 27787264;       // k (4096x512)
static const long VTB  = 29884416;       // v^T (512x4096)

// ---------------- dtype detection ----------------
__global__ void detect_dtype(const ushort* __restrict__ x, int* __restrict__ flag) {
  __shared__ int cnt;
  if (threadIdx.x == 0) cnt = 0;
  __syncthreads();
  int local = 0;
  for (int j = 0; j < 32; j++) {
    ushort u = x[threadIdx.x + j * 256];
    int e = (u >> 7) & 0xFF;
    if (e >= 100 && e <= 142) local++;
  }
  atomicAdd(&cnt, local);
  __syncthreads();
  if (threadIdx.x == 0) *flag = (cnt >= 6554) ? 1 : 0;
}

// ---------------- fused cast of all 7 inputs (no-op when already bf16) --------
__global__ void cast_all(const void* __restrict__ s0, const void* __restrict__ s1,
                         const void* __restrict__ s2, const void* __restrict__ s3,
                         const void* __restrict__ s4, const void* __restrict__ s5,
                         const void* __restrict__ s6,
                         ushort* __restrict__ d0, ushort* __restrict__ d1,
                         ushort* __restrict__ d2, ushort* __restrict__ d3,
                         ushort* __restrict__ d4, ushort* __restrict__ d5,
                         ushort* __restrict__ d6, const int* __restrict__ flag) {
  if (*flag) return;
  const long N = 2424832;
  for (long i = (long)blockIdx.x * blockDim.x + threadIdx.x; i < N;
       i += (long)gridDim.x * blockDim.x) {
    const float4* s; ushort* d; long off;
    if      (i < 1048576) { s = (const float4*)s0; d = d0; off = i; }
    else if (i < 1572864) { s = (const float4*)s1; d = d1; off = i - 1048576; }
    else if (i < 1703936) { s = (const float4*)s2; d = d2; off = i - 1572864; }
    else if (i < 1835008) { s = (const float4*)s3; d = d3; off = i - 1703936; }
    else if (i < 2359296) { s = (const float4*)s4; d = d4; off = i - 1835008; }
    else if (i < 2392064) { s = (const float4*)s5; d = d5; off = i - 2359296; }
    else                  { s = (const float4*)s6; d = d6; off = i - 2392064; }
    float4 a = s[2 * off], b = s[2 * off + 1];
    uint4 o;
    o.x = (unsigned)f2bf(a.x) | ((unsigned)f2bf(a.y) << 16);
    o.y = (unsigned)f2bf(a.z) | ((unsigned)f2bf(a.w) << 16);
    o.z = (unsigned)f2bf(b.x) | ((unsigned)f2bf(b.y) << 16);
    o.w = (unsigned)f2bf(b.z) | ((unsigned)f2bf(b.w) << 16);
    ((uint4*)d)[off] = o;
  }
}

// ---------------- bf16 GEMM body: C tile = A[M,K] * W[N,K]^T ----------------
__device__ __forceinline__ void gemm_body(
    const ushort* __restrict__ A, const ushort* __restrict__ W, void* __restrict__ C,
    int N, int K, int bm, int bn, bool ofp32, ushort* As, ushort* Ws) {
  const int tid = threadIdx.x;
  const int wave = tid >> 6, lane = tid & 63;
  const int quad = lane >> 4, l15 = lane & 15;
  const int wm = (wave >> 1) * 64, wn = (wave & 1) * 64;
  const int srow = tid >> 2, sk = (tid & 3) * 8;
  const ushort* Ap = A + (size_t)(bm + srow) * K + sk;
  const ushort* Wp = W + (size_t)(bn + srow) * K + sk;
  ushort* AsW = As + wave * 512;
  ushort* WsW = Ws + wave * 512;
  f32x4 acc[4][4] = {};
  for (int k0 = 0; k0 < K; k0 += 32) {
    __syncthreads();
    gl_lds16(Ap + k0, AsW);
    gl_lds16(Ap + (size_t)64 * K + k0, AsW + 2048);
    gl_lds16(Wp + k0, WsW);
    gl_lds16(Wp + (size_t)64 * K + k0, WsW + 2048);
    __syncthreads();
    bf16x8 af[4], wf[4];
#pragma unroll
    for (int t = 0; t < 4; t++)
      af[t] = *(const bf16x8*)&As[(wm + t * 16 + l15) * 32 + quad * 8];
#pragma unroll
    for (int t = 0; t < 4; t++)
      wf[t] = *(const bf16x8*)&Ws[(wn + t * 16 + l15) * 32 + quad * 8];
#pragma unroll
    for (int mt = 0; mt < 4; mt++)
#pragma unroll
      for (int nt = 0; nt < 4; nt++)
        acc[mt][nt] = __builtin_amdgcn_mfma_f32_16x16x32_bf16(af[mt], wf[nt], acc[mt][nt], 0, 0, 0);
  }
  if (!ofp32) {
    ushort* Cb = (ushort*)C;
#pragma unroll
    for (int mt = 0; mt < 4; mt++)
#pragma unroll
      for (int nt = 0; nt < 4; nt++)
#pragma unroll
        for (int r = 0; r < 4; r++) {
          int row = bm + wm + mt * 16 + quad * 4 + r;
          int col = bn + wn + nt * 16 + l15;
          Cb[(size_t)row * N + col] = f2bf(acc[mt][nt][r]);
        }
  } else {
    float* Cf = (float*)C;
#pragma unroll
    for (int mt = 0; mt < 4; mt++)
#pragma unroll
      for (int nt = 0; nt < 4; nt++)
#pragma unroll
        for (int r = 0; r < 4; r++) {
          int row = bm + wm + mt * 16 + quad * 4 + r;
          int col = bn + wn + nt * 16 + l15;
          Cf[(size_t)row * N + col] = acc[mt][nt][r];
        }
  }
}

// fused Q/K/V^T projection: 1D grid 768. [0,512) Q; [512,640) K; [640,768) V^T.
__global__ __launch_bounds__(256) void gemm_qkv(
    const ushort* __restrict__ xws, const ushort* __restrict__ xorig,
    const ushort* __restrict__ wqws, const ushort* __restrict__ wqorig,
    const ushort* __restrict__ wkws, const ushort* __restrict__ wkorig,
    const ushort* __restrict__ wvws, const ushort* __restrict__ wvorig,
    ushort* __restrict__ qout, ushort* __restrict__ kout, ushort* __restrict__ vtout,
    const int* __restrict__ flag) {
  __shared__ __align__(16) ushort As[128 * 32];
  __shared__ __align__(16) ushort Ws[128 * 32];
  const bool bf = (*flag != 0);
  const ushort* x = bf ? xorig : xws;
  const int id = blockIdx.x;
  if (id < 512) {
    gemm_body(x, bf ? wqorig : wqws, qout, 2048, 2048, (id >> 4) * 128, (id & 15) * 128, false, As, Ws);
  } else if (id < 640) {
    int t = id - 512;
    gemm_body(x, bf ? wkorig : wkws, kout, 512, 2048, (t >> 2) * 128, (t & 3) * 128, false, As, Ws);
  } else {
    int t = id - 640;
    gemm_body(bf ? wvorig : wvws, x, vtout, 4096, 2048, (t & 3) * 128, (t >> 2) * 128, false, As, Ws);
  }
}

__global__ __launch_bounds__(256) void gemm_bt(
    const ushort* __restrict__ Aws, const ushort* __restrict__ Aorig,
    const ushort* __restrict__ Wws, const ushort* __restrict__ Worig,
    void* __restrict__ C, int N, int K, const int* __restrict__ flag, int outMode) {
  __shared__ __align__(16) ushort As[128 * 32];
  __shared__ __align__(16) ushort Ws[128 * 32];
  const bool bf = (*flag != 0);
  const ushort* A = (bf && Aorig) ? Aorig : Aws;
  const ushort* W = (bf && Worig) ? Worig : Wws;
  bool ofp32 = (outMode == 1) && !bf;
  gemm_body(A, W, C, N, K, blockIdx.y * 128, blockIdx.x * 128, ofp32, As, Ws);
}

// ---------------- RoPE, vectorized: 16 elems/thread ----------------
__global__ void rope_kernel(ushort* __restrict__ Qb, ushort* __restrict__ Kb,
                            const ushort* __restrict__ cws, const ushort* __restrict__ corig,
                            const ushort* __restrict__ sws, const ushort* __restrict__ sorig,
                            const int* __restrict__ flag) {
  const ushort* cb = (*flag) ? corig : cws;
  const ushort* sb = (*flag) ? sorig : sws;
  int i = blockIdx.x * 256 + threadIdx.x;   // 0..655359
  ushort* base; long row; int c8; float scl;
  if (i < 524288) {
    row = i >> 7; int rest = i & 127; c8 = (rest & 3) * 8;
    base = Qb + row * 2048 + (rest >> 2) * 64 + c8;
    scl = 0.18033688011112f;   // 0.125 * log2(e)
  } else {
    int j = i - 524288;
    row = j >> 5; int rest = j & 31; c8 = (rest & 3) * 8;
    base = Kb + row * 512 + (rest >> 2) * 64 + c8;
    scl = 1.0f;
  }
  uint4 lo4 = *(const uint4*)base;
  uint4 hi4 = *(const uint4*)(base + 32);
  uint4 cl4 = *(const uint4*)(cb + row * 64 + c8);
  uint4 ch4 = *(const uint4*)(cb + row * 64 + c8 + 32);
  uint4 sl4 = *(const uint4*)(sb + row * 64 + c8);
  uint4 sh4 = *(const uint4*)(sb + row * 64 + c8 + 32);
  const ushort* lo = (const ushort*)&lo4; const ushort* hi = (const ushort*)&hi4;
  const ushort* cl = (const ushort*)&cl4; const ushort* ch = (const ushort*)&ch4;
  const ushort* sl = (const ushort*)&sl4; const ushort* sh = (const ushort*)&sh4;
  uint4 olo, ohi;
  ushort* po = (ushort*)&olo; ushort* ph = (ushort*)&ohi;
#pragma unroll
  for (int k = 0; k < 8; k++) {
    float l = bf2f(lo[k]), h = bf2f(hi[k]);
    po[k] = f2bf((l * bf2f(cl[k]) - h * bf2f(sl[k])) * scl);
    ph[k] = f2bf((h * bf2f(ch[k]) + l * bf2f(sh[k])) * scl);
  }
  *(uint4*)base = olo;
  *(uint4*)(base + 32) = ohi;
}

// ---------------- causal GQA flash attention ----------------
// 256 thr (4 waves), BM=128 (32 Q rows/wave). K/V tiles (64x64) staged in LDS
// via global_load_lds as two 32-col panels (row stride 32 us = 16 dw -> 2-way
// alias = free), shared by all 4 waves: L2 read traffic /4 vs register loads.
// Grid 512 = 64 bh x 8 tile-pairs; block does Q-tiles t and 15-t -> exactly 36
// KV iterations per block, exactly 2 blocks/CU. No launch_bounds (R4/R5 spill
// lesson: body needs ~100 VGPRs; capping causes 25-400MB scratch traffic).
__global__ void attn_kernel(
    const ushort* __restrict__ Qb, const ushort* __restrict__ Kb,
    const ushort* __restrict__ Vt, ushort* __restrict__ Ob) {
  __shared__ __align__(16) ushort Ks[4096];     // [kc][s][32]
  __shared__ __align__(16) ushort Vs[4096];     // [sc][d][32]
  __shared__ __align__(16) ushort Ps[128 * 72]; // [q][s], wave-private rows
  const int tid = threadIdx.x;
  const int wave = tid >> 6, lane = tid & 63;
  const int quad = lane >> 4, l15 = lane & 15;
  const int id = blockIdx.x;
  const int kvh = id & 7;                  // XCD-pinned KV head
  const int b = (id >> 3) & 1;
  const int hsub = (id >> 4) & 3;
  const int h = kvh * 4 + hsub;
  const int pr = id >> 6;                  // 0..7 tile-pair
  const size_t brow = (size_t)b * 2048;
  const ushort* Kg = Kb + brow * 512 + (size_t)kvh * 64;
  const ushort* Vg = Vt + (size_t)(kvh * 64) * 4096 + brow;

  // staging decode: each wave stages 2 of 8 1KB segments of K and of V.
  const int seg0 = wave * 2;
  const int prow0 = seg0 * 16 + (lane >> 2);      // panel-row for segment seg0
  const int chunk = (lane & 3) * 8;
  // K panel-row p: kc = p>>6, s = p&63 -> Kg[(n0+s)*512 + kc*32 + chunk]
  const int kA_s = prow0 & 63, kA_kc = prow0 >> 6;
  const int kB_s = (prow0 + 16) & 63, kB_kc = (prow0 + 16) >> 6;
  // V panel-row q: sc = q>>6, d = q&63 -> Vg[d*4096 + n0 + sc*32 + chunk]
  const int vA_d = prow0 & 63, vA_sc = prow0 >> 6;
  const int vB_d = (prow0 + 16) & 63, vB_sc = (prow0 + 16) >> 6;

  for (int ph = 0; ph < 2; ph++) {
    const int t = ph ? (15 - pr) : pr;     // 128-row Q-tile index
    const int q0 = t * 128;
    const int wrow0 = q0 + wave * 32;
    const int blockNt = 2 * t + 2;
    const int myLast = wrow0 >> 6;         // last KV tile this wave computes

    bf16x8 qf[2][2];
#pragma unroll
    for (int mt = 0; mt < 2; mt++)
#pragma unroll
      for (int kc = 0; kc < 2; kc++)
        qf[mt][kc] = *(const bf16x8*)&Qb[(brow + wrow0 + mt * 16 + l15) * 2048 + h * 64 + kc * 32 + quad * 8];

    float l_s[2][4] = {};
    f32x4 oacc[2][4] = {};

    for (int nt = 0; nt < blockNt; nt++) {
      const int n0 = nt * 64;
      __syncthreads();                     // prior tile's LDS reads done
      gl_lds16(Kg + (size_t)(n0 + kA_s) * 512 + kA_kc * 32 + chunk, Ks + seg0 * 512);
      gl_lds16(Kg + (size_t)(n0 + kB_s) * 512 + kB_kc * 32 + chunk, Ks + seg0 * 512 + 512);
      gl_lds16(Vg + (size_t)vA_d * 4096 + n0 + vA_sc * 32 + chunk, Vs + seg0 * 512);
      gl_lds16(Vg + (size_t)vB_d * 4096 + n0 + vB_sc * 32 + chunk, Vs + seg0 * 512 + 512);
      __syncthreads();                     // drain + barrier
      if (nt > myLast) continue;           // wave fully masked (barriers done)

      const bool diag = (nt == myLast);
#pragma unroll
      for (int mt = 0; mt < 2; mt++) {
        f32x4 sc[4];
#pragma unroll
        for (int ct = 0; ct < 4; ct++) {
          bf16x8 kf0 = *(const bf16x8*)&Ks[(ct * 16 + l15) * 32 + quad * 8];
          bf16x8 kf1 = *(const bf16x8*)&Ks[2048 + (ct * 16 + l15) * 32 + quad * 8];
          f32x4 z = {0.f, 0.f, 0.f, 0.f};
          z = __builtin_amdgcn_mfma_f32_16x16x32_bf16(qf[mt][0], kf0, z, 0, 0, 0);
          z = __builtin_amdgcn_mfma_f32_16x16x32_bf16(qf[mt][1], kf1, z, 0, 0, 0);
          sc[ct] = z;
        }
        const int rowb = wrow0 + mt * 16 + quad * 4;
        if (diag) {
#pragma unroll
          for (int ct = 0; ct < 4; ct++)
#pragma unroll
            for (int r = 0; r < 4; r++)
              if (n0 + ct * 16 + l15 > rowb + r) sc[ct][r] = -INFINITY;
        }
#pragma unroll
        for (int ct = 0; ct < 4; ct++)
#pragma unroll
          for (int r = 0; r < 4; r++) {
            float pv = EXP2F(sc[ct][r] - 23.083120654223f);
            l_s[mt][r] += pv;
            Ps[(wave * 32 + mt * 16 + quad * 4 + r) * 72 + ct * 16 + l15] =
                (ushort)((__float_as_uint(pv) + 0x8000u) >> 16);
          }
      }
      // wave-private P rows: no barrier needed
#pragma unroll
      for (int mt = 0; mt < 2; mt++) {
        bf16x8 pf0 = *(const bf16x8*)&Ps[(wave * 32 + mt * 16 + l15) * 72 + quad * 8];
        bf16x8 pf1 = *(const bf16x8*)&Ps[(wave * 32 + mt * 16 + l15) * 72 + 32 + quad * 8];
#pragma unroll
        for (int dt = 0; dt < 4; dt++) {
          bf16x8 vf0 = *(const bf16x8*)&Vs[(dt * 16 + l15) * 32 + quad * 8];
          bf16x8 vf1 = *(const bf16x8*)&Vs[2048 + (dt * 16 + l15) * 32 + quad * 8];
          oacc[mt][dt] = __builtin_amdgcn_mfma_f32_16x16x32_bf16(pf0, vf0, oacc[mt][dt], 0, 0, 0);
          oacc[mt][dt] = __builtin_amdgcn_mfma_f32_16x16x32_bf16(pf1, vf1, oacc[mt][dt], 0, 0, 0);
        }
      }
    }
#pragma unroll
    for (int mt = 0; mt < 2; mt++)
#pragma unroll
      for (int r = 0; r < 4; r++) {
        float l = l_s[mt][r];
#pragma unroll
        for (int off = 1; off < 16; off <<= 1) l += __shfl_xor(l, off, 64);
        l_s[mt][r] = 1.f / l;
      }
#pragma unroll
    for (int mt = 0; mt < 2; mt++)
#pragma unroll
      for (int dt = 0; dt < 4; dt++)
#pragma unroll
        for (int r = 0; r < 4; r++) {
          int s = wrow0 + mt * 16 + quad * 4 + r;
          Ob[(brow + s) * 2048 + h * 64 + dt * 16 + l15] = f2bf(oacc[mt][dt][r] * l_s[mt][r]);
        }
  }
}

extern "C" void kernel_launch(void* const* d_in, const int* in_sizes, int n_in,
                              void* d_out, int out_size, void* d_ws, size_t ws_size,
                              hipStream_t stream) {
  char* wsb = (char*)d_ws;
  int* flag = (int*)wsb;
  ushort* base = (ushort*)(wsb + 256);
  ushort* xb   = base + XB;
  ushort* wqb  = base + WQB;
  ushort* wkb  = base + WKB;
  ushort* wvb  = base + WVB;
  ushort* wob  = base + WOB;
  ushort* cosb = base + COSB;
  ushort* sinb = base + SINB;
  ushort* qb   = base + QB;
  ushort* kb   = base + KB;
  ushort* vtb  = base + VTB;
  ushort* abuf = xb;   // attn output reuses x region

  const ushort* xo  = (const ushort*)d_in[0];
  const ushort* co  = (const ushort*)d_in[1];
  const ushort* so  = (const ushort*)d_in[2];
  const ushort* wqo = (const ushort*)d_in[4];
  const ushort* wko = (const ushort*)d_in[5];
  const ushort* wvo = (const ushort*)d_in[6];
  const ushort* woo = (const ushort*)d_in[7];

  detect_dtype<<<1, 256, 0, stream>>>(xo, flag);

  cast_all<<<4096, 256, 0, stream>>>(d_in[0], d_in[4], d_in[5], d_in[6], d_in[7],
                                     d_in[1], d_in[2],
                                     xb, wqb, wkb, wvb, wob, cosb, sinb, flag);

  gemm_qkv<<<768, 256, 0, stream>>>(xb, xo, wqb, wqo, wkb, wko, wvb, wvo,
                                    qb, kb, vtb, flag);

  rope_kernel<<<2560, 256, 0, stream>>>(qb, kb, cosb, co, sinb, so, flag);

  attn_kernel<<<512, 256, 0, stream>>>(qb, kb, vtb, abuf);

  gemm_bt<<<dim3(16, 32), 256, 0, stream>>>(abuf, nullptr, wob, woo, d_out, 2048, 2048, flag, 1);
}